// Round 2
// baseline (2579.302 us; speedup 1.0000x reference)
//
#include <hip/hip_runtime.h>
#include <hip/hip_bf16.h>
#include <math.h>

typedef __hip_bfloat16 bf16;

#define L_    5
#define H_    1024
#define NH_   16
#define NKV_  8
#define HD_   128
#define I_    3072
#define MAXS_ 16
#define EPS_  1e-6f
#define KVE_  (L_ * NKV_ * MAXS_ * HD_)   // 81920 elements per cache tensor
#define GRID_ 512

static __device__ __forceinline__ float bl(unsigned u){ return __uint_as_float(u << 16); }
static __device__ __forceinline__ float bh(unsigned u){ return __uint_as_float(u & 0xffff0000u); }
static __device__ __forceinline__ float b2f(bf16 v){ return __bfloat162float(v); }

static __device__ __forceinline__ float wred(float v){
#pragma unroll
    for (int o = 32; o; o >>= 1) v += __shfl_xor(v, o, 64);
    return v;
}

static __device__ __forceinline__ float dot8(uint4 u, float4 a, float4 b){
    return bl(u.x)*a.x + bh(u.x)*a.y + bl(u.y)*a.z + bh(u.y)*a.w
         + bl(u.z)*b.x + bh(u.z)*b.y + bl(u.w)*b.z + bh(u.w)*b.w;
}

static __device__ __forceinline__ float rms_inv(float sumsq, float n){
    float a = sumsq / n + EPS_;
    float y = rsqrtf(a);
    y = y * (1.5f - 0.5f * a * y * y);
    return y;
}

// dtype-adaptive scalar load/store (element index, storage flag)
static __device__ __forceinline__ float ld1(const void* p, size_t i, bool b16){
    return b16 ? b2f(((const bf16*)p)[i]) : ((const float*)p)[i];
}
static __device__ __forceinline__ void st1(void* p, size_t i, float v, bool b16){
    if (b16) ((bf16*)p)[i] = __float2bfloat16(v);
    else     ((float*)p)[i] = v;
}

// wave-cooperative dot of one weight row (n elements, element offset `off`)
// against LDS vector hs[0..n). Returns per-lane partial (caller wred()s).
static __device__ __forceinline__ float rowdot(const void* w, size_t off, int n,
                                               const float* hs, bool b16, int lane){
    float acc = 0.f;
    if (b16) {
        const uint4* wp = (const uint4*)((const ushort*)w + off);
#pragma unroll 6
        for (int c = 0; c < n / 512; c++) {
            uint4 u = wp[c * 64 + lane];
            const float4* h4 = (const float4*)&hs[c * 512 + lane * 8];
            acc += dot8(u, h4[0], h4[1]);
        }
    } else {
        const float4* wp = (const float4*)((const float*)w + off);
#pragma unroll 12
        for (int c = 0; c < n / 256; c++) {
            float4 u = wp[c * 64 + lane];
            float4 h = *(const float4*)&hs[c * 256 + lane * 4];
            acc += u.x * h.x + u.y * h.y + u.z * h.z + u.w * h.w;
        }
    }
    return acc;
}

// ---------------------------------------------------------------------------
// Grid-wide barrier: all GRID_ blocks are resident by construction
// (__launch_bounds__(256,2), grid = 2 x 256 CUs). Sense-free arrive/release:
// cnt self-resets to 0 each barrier; gen increases monotonically within a run
// (prologue zeroes both each launch). __threadfence() both sides gives
// device-scope release/acquire across non-coherent per-XCD L2s.
// ---------------------------------------------------------------------------
static __device__ __forceinline__ void gsync(unsigned* cnt, unsigned* gen){
    __syncthreads();
    if (threadIdx.x == 0) {
        __threadfence();  // release: this block's writes -> device scope
        unsigned g = __hip_atomic_load(gen, __ATOMIC_RELAXED, __HIP_MEMORY_SCOPE_AGENT);
        unsigned a = __hip_atomic_fetch_add(cnt, 1u, __ATOMIC_ACQ_REL, __HIP_MEMORY_SCOPE_AGENT);
        if (a == GRID_ - 1) {
            __hip_atomic_store(cnt, 0u, __ATOMIC_RELAXED, __HIP_MEMORY_SCOPE_AGENT);
            __hip_atomic_fetch_add(gen, 1u, __ATOMIC_RELEASE, __HIP_MEMORY_SCOPE_AGENT);
        } else {
            while (__hip_atomic_load(gen, __ATOMIC_ACQUIRE, __HIP_MEMORY_SCOPE_AGENT) == g)
                __builtin_amdgcn_s_sleep(1);
        }
        __threadfence();  // acquire: invalidate stale cache before reading peers' data
    }
    __syncthreads();
}

// prologue: zero rms slots + barrier state (workspace persists across replays)
__global__ void k_zero(float* __restrict__ ws){
    float* ss = ws + 10240;
    if (threadIdx.x < 16) ss[threadIdx.x] = 0.f;
    if (threadIdx.x == 0) {
        unsigned* bar = (unsigned*)(ss + 16);
        bar[0] = 0u; bar[1] = 0u;
    }
}

// ---------------------------------------------------------------------------
// Single persistent kernel: whole 5-layer forward. 512 blocks x 256 threads.
// gsync() between stages replaces 33 kernel launches. RMS sum-of-squares is
// produced by the stage that writes x (one atomicAdd partial per block) so
// consumer stages never re-reduce.
// ss slots: iln uses ss[2l] (= previous stage's sum), paln ss[2l+1], final ss[10].
// ---------------------------------------------------------------------------
__global__ __launch_bounds__(256, 2) void k_model(
        const void* __restrict__ hid, const int* __restrict__ pos_p,
        const void* __restrict__ pk,  const void* __restrict__ pv,
        const void* __restrict__ w_iln, const void* __restrict__ w_paln,
        const void* __restrict__ wq,  const void* __restrict__ wk,
        const void* __restrict__ wv,  const void* __restrict__ wo,
        const void* __restrict__ w_qn, const void* __restrict__ w_kn,
        const void* __restrict__ w_gate, const void* __restrict__ w_up,
        const void* __restrict__ w_down, const void* __restrict__ w_onorm,
        float* __restrict__ ws, void* __restrict__ out)
{
    __shared__ float sh[I_];      // hs (1024) / attn stage-in (2048) / act (3072)
    __shared__ float red[4];

    const int gid = blockIdx.x, tid = threadIdx.x;
    const int lane = tid & 63, wid = tid >> 6;
    const bool b16 = (((const ushort*)w_onorm)[0] == 0x3F80);
    int pos = pos_p[0];
    pos = pos < 0 ? 0 : (pos > MAXS_ - 1 ? MAXS_ - 1 : pos);

    float* x    = ws;             // 1024
    float* qraw = x + 1024;       // 2048
    float* kraw = qraw + 2048;    // 1024
    float* vraw = kraw + 1024;    // 1024
    float* attn = vraw + 1024;    // 2048
    float* act  = attn + 2048;    // 3072  (ends at 10240)
    float* ss   = act + 3072;     // 16 slots
    unsigned* cnt = (unsigned*)(ss + 16);
    unsigned* gen = cnt + 1;

    // ---- init: copy past K/V into out, x = hidden, ss[0] = sum(x^2) ----
    {
        int gt = gid * 256 + tid;
        if (b16) {
            const int NV = KVE_ / 8;
            for (int i = gt; i < NV; i += GRID_ * 256) {
                ((uint4*)((bf16*)out + H_))[i]        = ((const uint4*)pk)[i];
                ((uint4*)((bf16*)out + H_ + KVE_))[i] = ((const uint4*)pv)[i];
            }
        } else {
            const int NV = KVE_ / 4;
            for (int i = gt; i < NV; i += GRID_ * 256) {
                ((uint4*)((float*)out + H_))[i]        = ((const uint4*)pk)[i];
                ((uint4*)((float*)out + H_ + KVE_))[i] = ((const uint4*)pv)[i];
            }
        }
        if (gid == 0) {
            float s0 = 0.f;
            for (int j = tid; j < H_; j += 256) {
                float v = ld1(hid, j, b16);
                x[j] = v; s0 += v * v;
            }
            s0 = wred(s0);
            if (lane == 0) red[wid] = s0;
            __syncthreads();
            if (tid == 0) ss[0] = red[0] + red[1] + red[2] + red[3];
        }
        gsync(cnt, gen);
    }

    for (int l = 0; l < L_; l++) {
        // ---- Stage Q: hs = rms(x)*w_iln; QKV GEMV (4096 rows, 8/block) ----
        {
            float inv = rms_inv(ss[2 * l], (float)H_);
            for (int j = tid; j < H_; j += 256)
                sh[j] = x[j] * inv * ld1(w_iln, (size_t)l * H_ + j, b16);
            __syncthreads();
            for (int rr = wid; rr < 8; rr += 4) {
                int r = gid * 8 + rr;
                const void* w; size_t off; float* dst;
                if (r < NH_ * HD_) {
                    w = wq; off = (size_t)l * NH_ * HD_ * H_ + (size_t)r * H_; dst = qraw + r;
                } else if (r < NH_ * HD_ + NKV_ * HD_) {
                    int rk = r - NH_ * HD_;
                    w = wk; off = (size_t)l * NKV_ * HD_ * H_ + (size_t)rk * H_; dst = kraw + rk;
                } else {
                    int rv = r - NH_ * HD_ - NKV_ * HD_;
                    w = wv; off = (size_t)l * NKV_ * HD_ * H_ + (size_t)rv * H_; dst = vraw + rv;
                }
                float acc = wred(rowdot(w, off, H_, sh, b16, lane));
                if (lane == 0) *dst = acc;
            }
            gsync(cnt, gen);
        }

        // ---- Stage A: fused q/k rms + rope + attention + cache write ----
        if (gid < NH_ && wid == 0) {
            int hh = gid, g = hh >> 1;
            float fr = (float)pos * exp2f(-(float)lane * 0.31143075889569023f);
            float c = cosf(fr), s = sinf(fr);

            float q0 = qraw[hh * HD_ + lane], q1 = qraw[hh * HD_ + 64 + lane];
            float qi = rms_inv(wred(q0 * q0 + q1 * q1), (float)HD_);
            q0 *= qi * ld1(w_qn, (size_t)l * HD_ + lane, b16);
            q1 *= qi * ld1(w_qn, (size_t)l * HD_ + 64 + lane, b16);
            float q0r = q0 * c - q1 * s, q1r = q1 * c + q0 * s;

            float k0 = kraw[g * HD_ + lane], k1 = kraw[g * HD_ + 64 + lane];
            float ki = rms_inv(wred(k0 * k0 + k1 * k1), (float)HD_);
            k0 *= ki * ld1(w_kn, (size_t)l * HD_ + lane, b16);
            k1 *= ki * ld1(w_kn, (size_t)l * HD_ + 64 + lane, b16);
            float k0r = k0 * c - k1 * s, k1r = k1 * c + k0 * s;

            float v0 = vraw[g * HD_ + lane], v1 = vraw[g * HD_ + 64 + lane];

            size_t kco = H_ + (size_t)l * NKV_ * MAXS_ * HD_ + (size_t)g * MAXS_ * HD_;
            size_t vco = kco + KVE_;
            const float scale = 0.08838834764831845f;  // 1/sqrt(128)

            float sc[MAXS_];
            float m = -3.0e38f;
#pragma unroll
            for (int t = 0; t < MAXS_; t++) {
                float d = (t == pos)
                    ? (q0r * k0r + q1r * k1r)
                    : (q0r * ld1(out, kco + t * HD_ + lane, b16)
                     + q1r * ld1(out, kco + t * HD_ + 64 + lane, b16));
                d = wred(d) * scale;
                sc[t] = d;
                if (t <= pos) m = fmaxf(m, d);
            }
            float se = 0.f;
#pragma unroll
            for (int t = 0; t < MAXS_; t++) {
                float e = (t <= pos) ? expf(sc[t] - m) : 0.0f;
                sc[t] = e; se += e;
            }
            float rinv = 1.0f / se;
            float a0 = 0.f, a1 = 0.f;
#pragma unroll
            for (int t = 0; t < MAXS_; t++) {
                float pt = sc[t] * rinv;
                if (t == pos) { a0 += pt * v0; a1 += pt * v1; }
                else {
                    a0 += pt * ld1(out, vco + t * HD_ + lane, b16);
                    a1 += pt * ld1(out, vco + t * HD_ + 64 + lane, b16);
                }
            }
            attn[hh * HD_ + lane]      = a0;
            attn[hh * HD_ + 64 + lane] = a1;
            if ((hh & 1) == 0) {
                st1(out, kco + pos * HD_ + lane,      k0r, b16);
                st1(out, kco + pos * HD_ + 64 + lane, k1r, b16);
                st1(out, vco + pos * HD_ + lane,      v0,  b16);
                st1(out, vco + pos * HD_ + 64 + lane, v1,  b16);
            }
        }
        gsync(cnt, gen);

        // ---- Stage O: x += wo@attn (1024 rows, blocks 0..255), ss[2l+1] ----
        if (gid < 256) {
            for (int j = tid; j < NH_ * HD_; j += 256) sh[j] = attn[j];
            __syncthreads();
            int r = gid * 4 + wid;
            size_t off = (size_t)l * H_ * NH_ * HD_ + (size_t)r * NH_ * HD_;
            float acc = wred(rowdot(wo, off, NH_ * HD_, sh, b16, lane));
            float xn = x[r] + acc;
            if (lane == 0) { x[r] = xn; red[wid] = xn * xn; }
            __syncthreads();
            if (tid == 0) atomicAdd(&ss[2 * l + 1], red[0] + red[1] + red[2] + red[3]);
        }
        gsync(cnt, gen);

        // ---- Stage G: hs = rms(x)*w_paln; act = silu(gate@hs)*(up@hs) ----
        {
            float inv = rms_inv(ss[2 * l + 1], (float)H_);
            for (int j = tid; j < H_; j += 256)
                sh[j] = x[j] * inv * ld1(w_paln, (size_t)l * H_ + j, b16);
            __syncthreads();
            for (int pp = wid; pp < 6; pp += 4) {
                int i = gid * 6 + pp;
                size_t off = (size_t)l * I_ * H_ + (size_t)i * H_;
                float ag = wred(rowdot(w_gate, off, H_, sh, b16, lane));
                float au = wred(rowdot(w_up,   off, H_, sh, b16, lane));
                if (lane == 0) {
                    float sig = 1.0f / (1.0f + expf(-ag));
                    act[i] = ag * sig * au;
                }
            }
            gsync(cnt, gen);
        }

        // ---- Stage D: x += w_down@act (1024 rows, blocks 0..255), ss[2l+2] ----
        if (gid < 256) {
            for (int j = tid; j < I_; j += 256) sh[j] = act[j];
            __syncthreads();
            int r = gid * 4 + wid;
            size_t off = (size_t)l * H_ * I_ + (size_t)r * I_;
            float acc = wred(rowdot(w_down, off, I_, sh, b16, lane));
            float xn = x[r] + acc;
            if (lane == 0) { x[r] = xn; red[wid] = xn * xn; }
            __syncthreads();
            if (tid == 0) atomicAdd(&ss[2 * l + 2], red[0] + red[1] + red[2] + red[3]);
        }
        gsync(cnt, gen);
    }

    // ---- final: out[0..H) = rms(x, w_onorm) ----
    if (gid == 0) {
        float inv = rms_inv(ss[10], (float)H_);
        for (int j = tid; j < H_; j += 256)
            st1(out, j, x[j] * inv * ld1(w_onorm, j, b16), b16);
    }
}

extern "C" void kernel_launch(void* const* d_in, const int* in_sizes, int n_in,
                              void* d_out, int out_size, void* d_ws, size_t ws_size,
                              hipStream_t stream) {
    const void* hid     = d_in[0];
    const int*  pos     = (const int*)d_in[1];
    const void* pk      = d_in[2];
    const void* pv      = d_in[3];
    const void* w_iln   = d_in[4];
    const void* w_paln  = d_in[5];
    const void* wq      = d_in[6];
    const void* wk      = d_in[7];
    const void* wv      = d_in[8];
    const void* wo      = d_in[9];
    const void* w_qn    = d_in[10];
    const void* w_kn    = d_in[11];
    const void* w_gate  = d_in[12];
    const void* w_up    = d_in[13];
    const void* w_down  = d_in[14];
    const void* w_onorm = d_in[15];
    float* ws = (float*)d_ws;

    k_zero<<<1, 64, 0, stream>>>(ws);
    k_model<<<GRID_, 256, 0, stream>>>(hid, pos, pk, pv, w_iln, w_paln,
                                       wq, wk, wv, wo, w_qn, w_kn,
                                       w_gate, w_up, w_down, w_onorm,
                                       ws, d_out);
}

// Round 3
// 498.871 us; speedup vs baseline: 5.1703x; 5.1703x over previous
//
#include <hip/hip_runtime.h>
#include <hip/hip_bf16.h>
#include <math.h>

typedef __hip_bfloat16 bf16;
typedef unsigned long long ull;

#define L_    5
#define H_    1024
#define NH_   16
#define NKV_  8
#define HD_   128
#define I_    3072
#define MAXS_ 16
#define EPS_  1e-6f
#define KVE_  (L_ * NKV_ * MAXS_ * HD_)   // 81920 elements per cache tensor
#define GRID_ 512
#define BAR_OFF 10496                     // float index of barrier area in ws

static __device__ __forceinline__ float bl(unsigned u){ return __uint_as_float(u << 16); }
static __device__ __forceinline__ float bh(unsigned u){ return __uint_as_float(u & 0xffff0000u); }
static __device__ __forceinline__ float b2f(bf16 v){ return __bfloat162float(v); }

static __device__ __forceinline__ float wred(float v){
#pragma unroll
    for (int o = 32; o; o >>= 1) v += __shfl_xor(v, o, 64);
    return v;
}

static __device__ __forceinline__ float dot8(uint4 u, float4 a, float4 b){
    return bl(u.x)*a.x + bh(u.x)*a.y + bl(u.y)*a.z + bh(u.y)*a.w
         + bl(u.z)*b.x + bh(u.z)*b.y + bl(u.w)*b.z + bh(u.w)*b.w;
}

static __device__ __forceinline__ float rms_inv(float sumsq, float n){
    float a = sumsq / n + EPS_;
    float y = rsqrtf(a);
    y = y * (1.5f - 0.5f * a * y * y);
    return y;
}

// ---- device-scope (LLC-coherent, sc1) relaxed scalar access for cross-block data
static __device__ __forceinline__ float gld(const float* p){
    return __hip_atomic_load((float*)p, __ATOMIC_RELAXED, __HIP_MEMORY_SCOPE_AGENT);
}
static __device__ __forceinline__ void gst(float* p, float v){
    __hip_atomic_store(p, v, __ATOMIC_RELAXED, __HIP_MEMORY_SCOPE_AGENT);
}
static __device__ __forceinline__ void gst8(ull* p, ull v){
    __hip_atomic_store(p, v, __ATOMIC_RELAXED, __HIP_MEMORY_SCOPE_AGENT);
}

// dtype-adaptive scalar load/store (element index, storage flag)
static __device__ __forceinline__ float ld1(const void* p, size_t i, bool b16){
    return b16 ? b2f(((const bf16*)p)[i]) : ((const float*)p)[i];
}
static __device__ __forceinline__ void st1(void* p, size_t i, float v, bool b16){
    if (b16) ((bf16*)p)[i] = __float2bfloat16(v);
    else     ((float*)p)[i] = v;
}

// wave-cooperative dot of one weight row (n elements, element offset `off`)
// against LDS vector hs[0..n). Returns per-lane partial (caller wred()s).
static __device__ __forceinline__ float rowdot(const void* w, size_t off, int n,
                                               const float* hs, bool b16, int lane){
    float acc = 0.f;
    if (b16) {
        const uint4* wp = (const uint4*)((const ushort*)w + off);
#pragma unroll 6
        for (int c = 0; c < n / 512; c++) {
            uint4 u = wp[c * 64 + lane];
            const float4* h4 = (const float4*)&hs[c * 512 + lane * 8];
            acc += dot8(u, h4[0], h4[1]);
        }
    } else {
        const float4* wp = (const float4*)((const float*)w + off);
#pragma unroll 12
        for (int c = 0; c < n / 256; c++) {
            float4 u = wp[c * 64 + lane];
            float4 h = *(const float4*)&hs[c * 256 + lane * 4];
            acc += u.x * h.x + u.y * h.y + u.z * h.z + u.w * h.w;
        }
    }
    return acc;
}

// ---------------------------------------------------------------------------
// Fence-free tree barrier. Monotone counters (no resets): phase p's targets
// are 32*p per sub-line and 16*p at the master. All cross-block data uses
// sc1 (LLC) atomics, so LLC serialization order IS the release order:
//   data stores drained (vmcnt(0) implied by __syncthreads) -> sub RMW ->
//   master RMW (data-dep) -> gen store (control-dep) -> spinners observe.
// Layout (float idx from ws): sub[g] at BAR_OFF+g*32 (128B apart, g<16),
// master at BAR_OFF+512, gen at BAR_OFF+544.
// ---------------------------------------------------------------------------
static __device__ __forceinline__ void gsync(unsigned* bar, unsigned p, int gid){
    __syncthreads();   // drains each wave's vmem ops before s_barrier
    if (threadIdx.x == 0) {
        unsigned* sub    = bar + ((gid >> 5) * 32);
        unsigned* master = bar + 512;
        unsigned* gen    = bar + 544;
        asm volatile("s_waitcnt vmcnt(0)" ::: "memory");
        unsigned a = __hip_atomic_fetch_add(sub, 1u, __ATOMIC_RELAXED, __HIP_MEMORY_SCOPE_AGENT) + 1u;
        if (a == 32u * p) {
            unsigned m = __hip_atomic_fetch_add(master, 1u, __ATOMIC_RELAXED, __HIP_MEMORY_SCOPE_AGENT) + 1u;
            if (m == 16u * p)
                __hip_atomic_store(gen, p, __ATOMIC_RELAXED, __HIP_MEMORY_SCOPE_AGENT);
        }
        while (__hip_atomic_load(gen, __ATOMIC_RELAXED, __HIP_MEMORY_SCOPE_AGENT) < p)
            __builtin_amdgcn_s_sleep(8);
        asm volatile("" ::: "memory");
    }
    __syncthreads();
}

// prologue: zero rms slots + barrier state (workspace persists across replays)
__global__ void k_zero(float* __restrict__ ws){
    int t = threadIdx.x;
    if (t < 16) ws[10240 + t] = 0.f;
    unsigned* bar = (unsigned*)(ws + BAR_OFF);
    for (int i = t; i < 576; i += 256) bar[i] = 0u;
}

// ---------------------------------------------------------------------------
// Single persistent kernel: whole 5-layer forward. 512 blocks x 256 threads.
// ss slots: iln uses ss[2l], paln ss[2l+1], final ss[10].
// ---------------------------------------------------------------------------
__global__ __launch_bounds__(256, 2) void k_model(
        const void* __restrict__ hid, const int* __restrict__ pos_p,
        const void* __restrict__ pk,  const void* __restrict__ pv,
        const void* __restrict__ w_iln, const void* __restrict__ w_paln,
        const void* __restrict__ wq,  const void* __restrict__ wk,
        const void* __restrict__ wv,  const void* __restrict__ wo,
        const void* __restrict__ w_qn, const void* __restrict__ w_kn,
        const void* __restrict__ w_gate, const void* __restrict__ w_up,
        const void* __restrict__ w_down, const void* __restrict__ w_onorm,
        float* __restrict__ ws, void* __restrict__ out)
{
    __shared__ float sh[I_];      // hs (1024) / attn stage-in (2048) / act (3072)
    __shared__ float red[4];
    __shared__ float s_inv;

    const int gid = blockIdx.x, tid = threadIdx.x;
    const int lane = tid & 63, wid = tid >> 6;
    const bool b16 = (((const ushort*)w_onorm)[0] == 0x3F80);
    int pos = pos_p[0];
    pos = pos < 0 ? 0 : (pos > MAXS_ - 1 ? MAXS_ - 1 : pos);

    float* x    = ws;             // 1024
    float* qraw = x + 1024;       // 2048
    float* kraw = qraw + 2048;    // 1024
    float* vraw = kraw + 1024;    // 1024
    float* attn = vraw + 1024;    // 2048
    float* act  = attn + 2048;    // 3072  (ends at 10240)
    float* ss   = ws + 10240;     // 16 slots
    unsigned* bar = (unsigned*)(ws + BAR_OFF);
    unsigned ph = 0;

    // ---- init: K/V copy via sc1 8B stores (straight to LLC, no fence needed),
    //      x = hidden via sc1, ss[0] = sum(x^2) ----
    {
        const size_t esz = b16 ? 2 : 4;
        const size_t nll = (size_t)KVE_ * esz / 8;   // 8-byte units per tensor
        const ull* sk = (const ull*)pk;
        const ull* sv = (const ull*)pv;
        ull* dk = (ull*)((char*)out + (size_t)H_ * esz);
        ull* dv = dk + nll;
        for (size_t i = (size_t)gid * 256 + tid; i < nll; i += (size_t)GRID_ * 256) {
            gst8(dk + i, sk[i]);
            gst8(dv + i, sv[i]);
        }
        if (gid == 0) {
            float s0 = 0.f;
            for (int j = tid; j < H_; j += 256) {
                float v = ld1(hid, j, b16);
                gst(&x[j], v); s0 += v * v;
            }
            s0 = wred(s0);
            if (lane == 0) red[wid] = s0;
            __syncthreads();
            if (tid == 0) gst(&ss[0], red[0] + red[1] + red[2] + red[3]);
        }
        gsync(bar, ++ph, gid);
    }

    for (int l = 0; l < L_; l++) {
        // ---- Stage Q: hs = rms(x)*w_iln; QKV GEMV (4096 rows, 8/block) ----
        {
            if (tid == 0) s_inv = rms_inv(gld(&ss[2 * l]), (float)H_);
            __syncthreads();
            float inv = s_inv;
            for (int j = tid; j < H_; j += 256)
                sh[j] = gld(&x[j]) * inv * ld1(w_iln, (size_t)l * H_ + j, b16);
            __syncthreads();
            for (int rr = wid; rr < 8; rr += 4) {
                int r = gid * 8 + rr;
                const void* w; size_t off; float* dst;
                if (r < NH_ * HD_) {
                    w = wq; off = (size_t)l * NH_ * HD_ * H_ + (size_t)r * H_; dst = qraw + r;
                } else if (r < NH_ * HD_ + NKV_ * HD_) {
                    int rk = r - NH_ * HD_;
                    w = wk; off = (size_t)l * NKV_ * HD_ * H_ + (size_t)rk * H_; dst = kraw + rk;
                } else {
                    int rv = r - NH_ * HD_ - NKV_ * HD_;
                    w = wv; off = (size_t)l * NKV_ * HD_ * H_ + (size_t)rv * H_; dst = vraw + rv;
                }
                float acc = wred(rowdot(w, off, H_, sh, b16, lane));
                if (lane == 0) gst(dst, acc);
            }
            gsync(bar, ++ph, gid);
        }

        // ---- Stage A: fused q/k rms + rope + attention + cache write ----
        if (gid < NH_ && wid == 0) {
            int hh = gid, g = hh >> 1;
            float fr = (float)pos * exp2f(-(float)lane * 0.31143075889569023f);
            float c = cosf(fr), s = sinf(fr);

            float q0 = gld(&qraw[hh * HD_ + lane]), q1 = gld(&qraw[hh * HD_ + 64 + lane]);
            float qi = rms_inv(wred(q0 * q0 + q1 * q1), (float)HD_);
            q0 *= qi * ld1(w_qn, (size_t)l * HD_ + lane, b16);
            q1 *= qi * ld1(w_qn, (size_t)l * HD_ + 64 + lane, b16);
            float q0r = q0 * c - q1 * s, q1r = q1 * c + q0 * s;

            float k0 = gld(&kraw[g * HD_ + lane]), k1 = gld(&kraw[g * HD_ + 64 + lane]);
            float ki = rms_inv(wred(k0 * k0 + k1 * k1), (float)HD_);
            k0 *= ki * ld1(w_kn, (size_t)l * HD_ + lane, b16);
            k1 *= ki * ld1(w_kn, (size_t)l * HD_ + 64 + lane, b16);
            float k0r = k0 * c - k1 * s, k1r = k1 * c + k0 * s;

            float v0 = gld(&vraw[g * HD_ + lane]), v1 = gld(&vraw[g * HD_ + 64 + lane]);

            size_t kco = H_ + (size_t)l * NKV_ * MAXS_ * HD_ + (size_t)g * MAXS_ * HD_;
            size_t vco = kco + KVE_;
            const float scale = 0.08838834764831845f;  // 1/sqrt(128)

            float sc[MAXS_];
            float m = -3.0e38f;
#pragma unroll
            for (int t = 0; t < MAXS_; t++) {
                float d = (t == pos)
                    ? (q0r * k0r + q1r * k1r)
                    : (q0r * ld1(out, kco + t * HD_ + lane, b16)
                     + q1r * ld1(out, kco + t * HD_ + 64 + lane, b16));
                d = wred(d) * scale;
                sc[t] = d;
                if (t <= pos) m = fmaxf(m, d);
            }
            float se = 0.f;
#pragma unroll
            for (int t = 0; t < MAXS_; t++) {
                float e = (t <= pos) ? expf(sc[t] - m) : 0.0f;
                sc[t] = e; se += e;
            }
            float rinv = 1.0f / se;
            float a0 = 0.f, a1 = 0.f;
#pragma unroll
            for (int t = 0; t < MAXS_; t++) {
                float pt = sc[t] * rinv;
                if (t == pos) { a0 += pt * v0; a1 += pt * v1; }
                else {
                    a0 += pt * ld1(out, vco + t * HD_ + lane, b16);
                    a1 += pt * ld1(out, vco + t * HD_ + 64 + lane, b16);
                }
            }
            gst(&attn[hh * HD_ + lane],      a0);
            gst(&attn[hh * HD_ + 64 + lane], a1);
            if ((hh & 1) == 0) {
                st1(out, kco + pos * HD_ + lane,      k0r, b16);
                st1(out, kco + pos * HD_ + 64 + lane, k1r, b16);
                st1(out, vco + pos * HD_ + lane,      v0,  b16);
                st1(out, vco + pos * HD_ + 64 + lane, v1,  b16);
            }
        }
        gsync(bar, ++ph, gid);

        // ---- Stage O: x += wo@attn (1024 rows, blocks 0..255), ss[2l+1] ----
        if (gid < 256) {
            for (int j = tid; j < NH_ * HD_; j += 256) sh[j] = gld(&attn[j]);
            __syncthreads();
            int r = gid * 4 + wid;
            size_t off = (size_t)l * H_ * NH_ * HD_ + (size_t)r * NH_ * HD_;
            float acc = wred(rowdot(wo, off, NH_ * HD_, sh, b16, lane));
            if (lane == 0) {
                float xn = gld(&x[r]) + acc;
                gst(&x[r], xn);
                red[wid] = xn * xn;
            }
            __syncthreads();
            if (tid == 0) atomicAdd(&ss[2 * l + 1], red[0] + red[1] + red[2] + red[3]);
        }
        gsync(bar, ++ph, gid);

        // ---- Stage G: hs = rms(x)*w_paln; act = silu(gate@hs)*(up@hs) ----
        {
            if (tid == 0) s_inv = rms_inv(gld(&ss[2 * l + 1]), (float)H_);
            __syncthreads();
            float inv = s_inv;
            for (int j = tid; j < H_; j += 256)
                sh[j] = gld(&x[j]) * inv * ld1(w_paln, (size_t)l * H_ + j, b16);
            __syncthreads();
            for (int pp = wid; pp < 6; pp += 4) {
                int i = gid * 6 + pp;
                size_t off = (size_t)l * I_ * H_ + (size_t)i * H_;
                float ag = wred(rowdot(w_gate, off, H_, sh, b16, lane));
                float au = wred(rowdot(w_up,   off, H_, sh, b16, lane));
                if (lane == 0) {
                    float sig = 1.0f / (1.0f + expf(-ag));
                    gst(&act[i], ag * sig * au);
                }
            }
            gsync(bar, ++ph, gid);
        }

        // ---- Stage D: x += w_down@act (1024 rows, blocks 0..255), ss[2l+2] ----
        if (gid < 256) {
            for (int j = tid; j < I_; j += 256) sh[j] = gld(&act[j]);
            __syncthreads();
            int r = gid * 4 + wid;
            size_t off = (size_t)l * H_ * I_ + (size_t)r * I_;
            float acc = wred(rowdot(w_down, off, I_, sh, b16, lane));
            if (lane == 0) {
                float xn = gld(&x[r]) + acc;
                gst(&x[r], xn);
                red[wid] = xn * xn;
            }
            __syncthreads();
            if (tid == 0) atomicAdd(&ss[2 * l + 2], red[0] + red[1] + red[2] + red[3]);
        }
        gsync(bar, ++ph, gid);
    }

    // ---- final: out[0..H) = rms(x, w_onorm) ----
    if (gid == 0) {
        if (tid == 0) s_inv = rms_inv(gld(&ss[10]), (float)H_);
        __syncthreads();
        float inv = s_inv;
        for (int j = tid; j < H_; j += 256)
            st1(out, j, gld(&x[j]) * inv * ld1(w_onorm, j, b16), b16);
    }
}

extern "C" void kernel_launch(void* const* d_in, const int* in_sizes, int n_in,
                              void* d_out, int out_size, void* d_ws, size_t ws_size,
                              hipStream_t stream) {
    const void* hid     = d_in[0];
    const int*  pos     = (const int*)d_in[1];
    const void* pk      = d_in[2];
    const void* pv      = d_in[3];
    const void* w_iln   = d_in[4];
    const void* w_paln  = d_in[5];
    const void* wq      = d_in[6];
    const void* wk      = d_in[7];
    const void* wv      = d_in[8];
    const void* wo      = d_in[9];
    const void* w_qn    = d_in[10];
    const void* w_kn    = d_in[11];
    const void* w_gate  = d_in[12];
    const void* w_up    = d_in[13];
    const void* w_down  = d_in[14];
    const void* w_onorm = d_in[15];
    float* ws = (float*)d_ws;

    k_zero<<<1, 256, 0, stream>>>(ws);
    k_model<<<GRID_, 256, 0, stream>>>(hid, pos, pk, pv, w_iln, w_paln,
                                       wq, wk, wv, wo, w_qn, w_kn,
                                       w_gate, w_up, w_down, w_onorm,
                                       ws, d_out);
}